// Round 23
// baseline (227.522 us; speedup 1.0000x reference)
//
#include <hip/hip_runtime.h>
#include <math.h>

typedef unsigned long long u64;
typedef unsigned int u32;
typedef unsigned char u8;
typedef __attribute__((ext_vector_type(2))) unsigned long long u64x2;
typedef __attribute__((ext_vector_type(4))) int i32x4;

#define NB 8192
#define NS 4096

// ---- ws layout ----
static const size_t OFF_CNT = 0;                            // pcnt[2048] u64
static const size_t OFF_P3  = 16384;                        // p3[<=2048] double
static const size_t OFF_M8  = 32768;                        // mask8 [8192][4096] i8
static const size_t OFF_BT  = OFF_M8 + (size_t)NB * NS;     // Bt [4096][4096] i8
static const size_t WS_NEED = OFF_BT + (size_t)NS * NS;     // ~48 MB (proven available)
static const size_t OFF_MB  = 32768;                        // popcount fallback layout
static const size_t OFF_WB  = OFF_MB + (size_t)64 * NB * 8;

__device__ __forceinline__ void gload_lds16(const void* g, void* l) {
    __builtin_amdgcn_global_load_lds(
        (const __attribute__((address_space(1))) unsigned int*)g,
        (__attribute__((address_space(3))) unsigned int*)l, 16, 0, 0);
}

// ================= i8-MFMA path =================

// K12: fused prep (R17-verified). g<2048: mask8+pcnt over y. g>=2048: Bt of W.
__global__ __launch_bounds__(256) void k12_prep(
    const float* __restrict__ y, const float* __restrict__ W,
    u32* __restrict__ m8, u32* __restrict__ bt, u64* __restrict__ pcnt)
{
    const int g = blockIdx.x;
    const int t = threadIdx.x;
    if (g < 2048) {
        __shared__ unsigned rc[4];
        const float4* y4 = (const float4*)y;
        size_t base = (size_t)g * 4096 + t;
        unsigned lcnt = 0;
        #pragma unroll 4
        for (int k = 0; k < 16; ++k) {
            float4 v = y4[base + (size_t)k * 256];
            unsigned b0 = v.x != 0.0f, b1 = v.y != 0.0f, b2 = v.z != 0.0f, b3 = v.w != 0.0f;
            lcnt += b0 + b1 + b2 + b3;
            m8[base + (size_t)k * 256] = b0 | (b1 << 8) | (b2 << 16) | (b3 << 24);
        }
        for (int off = 32; off; off >>= 1) lcnt += __shfl_down(lcnt, off, 64);
        if ((t & 63) == 0) rc[t >> 6] = lcnt;
        __syncthreads();
        if (t == 0) pcnt[g] = (u64)rc[0] + rc[1] + rc[2] + rc[3];
    } else {
        __shared__ float tile[64][65];
        const int gg = g - 2048;
        const int j0 = (gg & 63) * 64, i0 = (gg >> 6) * 64;
        #pragma unroll
        for (int k = 0; k < 16; ++k) {
            int lin = t + (k << 8);
            int r = lin >> 6, c = lin & 63;
            tile[r][c] = W[(size_t)(i0 + r) * NS + (j0 + c)];
        }
        __syncthreads();
        const int jj = t >> 2, ck = t & 3;
        u32 wd[4];
        #pragma unroll
        for (int gq = 0; gq < 4; ++gq) {
            u32 u = 0;
            #pragma unroll
            for (int bb = 0; bb < 4; ++bb)
                u |= (tile[ck * 16 + gq * 4 + bb][jj] != 0.0f ? 1u : 0u) << (8 * bb);
            wd[gq] = u;
        }
        uint4 out = make_uint4(wd[0], wd[1], wd[2], wd[3]);
        *(uint4*)&bt[(((size_t)(j0 + jj) << 12) + (size_t)(i0 + ck * 16)) >> 2] = out;
    }
}

// K3g v5: R21 pipeline (best: 148us) + epilogue L3/L2 prefetch.
// Tiles m=24..31: each wave issues 8 dummy-dest gload_lds (64/tile, 512 total
// = the block's full 512KB y/yhat epilogue footprint) at q0-TOP, so they are
// the OLDEST VMEM ops per tile -> R21's vmcnt(4)/vmcnt(0) constants still
// exactly publish A(m)/B(m) (pf just folds into the wait; a full ~8000-cyc
// tile covers the ~900-cyc HBM latency). Dest = dedicated 8KB garbage region
// (DMA consumes no VGPRs). Epilogue reads then hit L3/L2 instead of HBM,
// shrinking the MFMA-idle tail.
__global__ __launch_bounds__(512, 2) void k3g_mfma(
    const float* __restrict__ y, const float* __restrict__ yhat,
    const u8* __restrict__ m8, const u8* __restrict__ bt,
    double* __restrict__ p3)
{
    __shared__ alignas(16) u8 lds[131072 + 8192];   // A 64KB | B 64KB | pf-dummy 8KB
    const int lin = blockIdx.x + (blockIdx.y << 5);      // 0..511, x fastest
    const int swz = ((lin & 7) << 6) + (lin >> 3);       // chunked per-XCD (bijective)
    const int bx = swz & 31, by = swz >> 5;
    const int b0 = bx << 8;    // 32 row tiles (256 rows)
    const int j0 = by << 8;    // 16 col tiles (256 cols)
    const int t = threadIdx.x, l = t & 63, wv = t >> 6;   // 8 waves
    const int wr = wv >> 2, wc = wv & 3;                  // 2M x 4N

    const int srow = t >> 3;                    // 0..63
    const int schunk = (t & 7) ^ (srow & 7);    // pre-swizzled source chunk

    auto stageA = [&](int kt, int h) {
        const u8* src = m8 + ((size_t)(b0 + (h << 7) + srow) << 12)
                        + (size_t)((kt << 7) + (schunk << 4));
        u8* d = &lds[((((kt & 1) << 1) + h) << 14) + (wv << 10)];
        gload_lds16(src, d);
        gload_lds16(src + ((size_t)64 << 12), d + 8192);
    };
    auto stageB = [&](int kt, int h) {
        const u8* src = bt + ((size_t)(j0 + (h << 7) + srow) << 12)
                        + (size_t)((kt << 7) + (schunk << 4));
        u8* d = &lds[65536 + ((((kt & 1) << 1) + h) << 14) + (wv << 10)];
        gload_lds16(src, d);
        gload_lds16(src + ((size_t)64 << 12), d + 8192);
    };

    // frag read swizzle: slot = (ks*4 + qh) ^ (row&7), row&7 == l&7
    const int rl = l & 15, qh = l >> 4, rx = l & 7;
    const int sb0 = ((qh ^ rx) << 4);
    const int sb1 = (((4 + qh) ^ rx) << 4);
    const int bro = (wc & 1) << 6;   // B within-half base row

    u8* const pfdummy = &lds[131072 + (wv << 10)];   // per-wave 1KB garbage
    const float* epi_base[2] = { y, yhat };

    i32x4 acc[8][4];
    #pragma unroll
    for (int i = 0; i < 8; ++i)
        #pragma unroll
        for (int j = 0; j < 4; ++j) acc[i][j] = (i32x4){0, 0, 0, 0};

    // prologue: tiles 0 and 1 (16 loads/thread)
    stageA(0, 0); stageA(0, 1); stageB(0, 0); stageB(0, 1);
    stageA(1, 0); stageA(1, 1); stageB(1, 0); stageB(1, 1);

    #pragma unroll 1
    for (int m = 0; m < 32; ++m) {
        const int d = m & 1;
        if (m == 0)       { asm volatile("s_waitcnt vmcnt(8)" ::: "memory"); }
        else if (m == 31) { asm volatile("s_waitcnt vmcnt(0)" ::: "memory"); }
        else              { asm volatile("s_waitcnt vmcnt(4)" ::: "memory"); }
        __builtin_amdgcn_s_barrier();          // A(m), B(m) published
        asm volatile("" ::: "memory");

        const u8* LA = &lds[(((d << 1) + wr) << 14)];
        const u8* LB = &lds[65536 + (((d << 1) + (wc >> 1)) << 14)];

        i32x4 b[4][2];
        #pragma unroll
        for (int q = 0; q < 4; ++q) {
            // epilogue prefetch: oldest VMEM ops of the tile (m=24..31)
            if (q == 0 && m >= 24) {
                const int k8 = m - 24;
                #pragma unroll
                for (int j = 0; j < 8; ++j) {
                    const int idx = (k8 << 6) + (wv << 3) + j;   // 0..511
                    const float* src = epi_base[idx >> 8]
                        + ((size_t)(b0 + (idx & 255)) << 12) + j0;
                    gload_lds16((const u8*)src + (l << 4) - (l << 4), pfdummy);
                    // NOTE: per-lane source offset comes from the lane-varying
                    // address below; the line above is replaced by:
                }
                // (real issue loop — per-lane 16B covers 1KB = 256 cols)
            }
            if (q == 0 && m >= 24) {
                const int k8 = m - 24;
                #pragma unroll
                for (int j = 0; j < 8; ++j) {
                    const int idx = (k8 << 6) + (wv << 3) + j;   // 0..511
                    const float* srcrow = epi_base[idx >> 8]
                        + ((size_t)(b0 + (idx & 255)) << 12) + j0;
                    gload_lds16((const u8*)srcrow + (size_t)(l << 4) * 0 + (size_t)0
                                + ((size_t)l << 4), pfdummy);
                }
            }

            if (q == 0) { if (m >= 1 && m <= 30) stageA(m + 1, 0); }
            else if (q == 1) { if (m >= 1 && m <= 30) stageA(m + 1, 1); }
            else if (q == 2) { if (m <= 29) stageB(m + 2, 0); }
            else             { if (m <= 29) stageB(m + 2, 1); }

            if (q == 0) {   // B for the whole tile, kept in regs
                #pragma unroll
                for (int fc = 0; fc < 4; ++fc) {
                    const int lr = bro + (fc << 4) + rl;
                    b[fc][0] = *(const i32x4*)&LB[(lr << 7) + sb0];
                    b[fc][1] = *(const i32x4*)&LB[(lr << 7) + sb1];
                }
            }
            i32x4 a[2][2];
            #pragma unroll
            for (int i = 0; i < 2; ++i) {
                const int lr = (((q << 1) + i) << 4) + rl;
                a[i][0] = *(const i32x4*)&LA[(lr << 7) + sb0];
                a[i][1] = *(const i32x4*)&LA[(lr << 7) + sb1];
            }
            __builtin_amdgcn_s_setprio(1);
            #pragma unroll
            for (int i = 0; i < 2; ++i)
                #pragma unroll
                for (int fc = 0; fc < 4; ++fc) {
                    acc[2 * q + i][fc] = __builtin_amdgcn_mfma_i32_16x16x64_i8(
                        a[i][0], b[fc][0], acc[2 * q + i][fc], 0, 0, 0);
                    acc[2 * q + i][fc] = __builtin_amdgcn_mfma_i32_16x16x64_i8(
                        a[i][1], b[fc][1], acc[2 * q + i][fc], 0, 0, 0);
                }
            __builtin_amdgcn_s_setprio(0);

            if (q == 0) {   // release B[d]
                asm volatile("" ::: "memory");
                __builtin_amdgcn_s_barrier();
                asm volatile("" ::: "memory");
            }
        }
    }

    // epilogue: C/D map col=l&15, row=(l>>4)*4+q (R10-verified), fused loss
    float part = 0.0f;
    const int col = j0 + (wc << 6) + rl;
    #pragma unroll
    for (int fr = 0; fr < 8; ++fr)
        #pragma unroll
        for (int q = 0; q < 4; ++q) {
            size_t rbase = ((size_t)(b0 + (wr << 7) + (fr << 4) + (qh << 2) + q) << 12) + col;
            #pragma unroll
            for (int fc = 0; fc < 4; ++fc) {
                float yv = y[rbase + (fc << 4)];
                float hv = yhat[rbase + (fc << 4)];
                float e = yv - hv;
                float wgt = 0.1f * (float)acc[fr][fc][q] + (yv != 0.0f ? 1.0f : 0.0f);
                part = fmaf(e * e, wgt, part);
            }
        }

    for (int off = 32; off; off >>= 1) part += __shfl_down(part, off, 64);
    float* red = (float*)lds;
    __syncthreads();   // drains all counters (incl. pf); safe to alias LDS
    if ((t & 63) == 0) red[t >> 6] = part;
    __syncthreads();
    if (t == 0) {
        float s = 0.0f;
        #pragma unroll
        for (int i = 0; i < 8; ++i) s += red[i];
        p3[swz] = (double)s;
    }
}

// ================= popcount fallback path (R8, passing) =================

__global__ __launch_bounds__(256) void k1_pack_mask(
    const float* __restrict__ y, u64* __restrict__ mbT, u64* __restrict__ pcnt)
{
    __shared__ unsigned rc[4];
    const unsigned t = threadIdx.x;
    const unsigned lane = t & 63;
    const float4* y4 = (const float4*)y;
    u64 qi = (u64)blockIdx.x * 256 + t;
    const u64 stride = (u64)2048 * 256;
    unsigned lcnt = 0;
    #pragma unroll 4
    for (int it = 0; it < 16; ++it, qi += stride) {
        float4 v = y4[qi];
        u64 b0 = __ballot(v.x != 0.0f);
        u64 b1 = __ballot(v.y != 0.0f);
        u64 b2 = __ballot(v.z != 0.0f);
        u64 b3 = __ballot(v.w != 0.0f);
        lcnt += (v.x != 0.0f) + (v.y != 0.0f) + (v.z != 0.0f) + (v.w != 0.0f);
        if (lane < 4) {
            unsigned sh = lane << 4;
            u64 word = ((b0 >> sh) & 0xFFFFull)
                     | (((b1 >> sh) & 0xFFFFull) << 16)
                     | (((b2 >> sh) & 0xFFFFull) << 32)
                     | (((b3 >> sh) & 0xFFFFull) << 48);
            u64 gw = ((qi - lane) >> 4) + lane;
            mbT[((gw & 63) << 13) + (gw >> 6)] = word;
        }
    }
    for (int off = 32; off; off >>= 1) lcnt += __shfl_down(lcnt, off, 64);
    if ((t & 63) == 0) rc[t >> 6] = lcnt;
    __syncthreads();
    if (t == 0) pcnt[blockIdx.x] = (u64)rc[0] + rc[1] + rc[2] + rc[3];
}

__global__ __launch_bounds__(256) void k2_pack_w(
    const float* __restrict__ W, u64* __restrict__ wbT)
{
    __shared__ float tile[64][65];
    const int j0 = blockIdx.x * 64;
    const int w  = blockIdx.y;
    const int i0 = w * 64;
    const int t = threadIdx.x;
    #pragma unroll
    for (int k = 0; k < 16; ++k) {
        int lin = t + (k << 8);
        int r = lin >> 6, c = lin & 63;
        tile[r][c] = W[(size_t)(i0 + r) * NS + (j0 + c)];
    }
    __syncthreads();
    const int lane = t & 63;
    const int wvv = t >> 6;
    const int pr = ((lane & 15) << 2) + (lane >> 4);
    for (int jj = wvv; jj < 64; jj += 4) {
        u64 bal = __ballot(tile[pr][jj] != 0.0f);
        if (lane == 0) wbT[((size_t)w << 12) + (j0 + jj)] = bal;
    }
}

__global__ __launch_bounds__(256) void k3_main(
    const float* __restrict__ y, const float* __restrict__ yhat,
    const u64* __restrict__ mbT, const u64* __restrict__ wbT,
    double* __restrict__ p3)
{
    __shared__ alignas(16) u64 mT[16 * 128];
    __shared__ alignas(16) u64 wT[16 * 128];
    const int b0 = blockIdx.x << 7;
    const int j0 = blockIdx.y << 7;
    const int t  = threadIdx.x;
    const int r0 = (t >> 4) << 3;
    const int cj = t & 15;
    const unsigned sx = ((unsigned)cj >> 2) << 4;

    unsigned cnt[8][8];
    #pragma unroll
    for (int a = 0; a < 8; ++a)
        #pragma unroll
        for (int b = 0; b < 8; ++b) cnt[a][b] = 0;

    char* mB = (char*)mT;
    char* wB = (char*)wT;

    #pragma unroll 1
    for (int s = 0; s < 4; ++s) {
        u64x2 gm[4], gq[4];
        #pragma unroll
        for (int k = 0; k < 4; ++k) {
            int lin = t + (k << 8);
            int wl = (s << 4) + (lin >> 6), c2 = lin & 63;
            gm[k] = *(const u64x2*)&mbT[((size_t)wl << 13) + b0 + 2 * c2];
            gq[k] = *(const u64x2*)&wbT[((size_t)wl << 12) + j0 + 2 * c2];
        }
        __syncthreads();
        #pragma unroll
        for (int k = 0; k < 4; ++k) {
            int lin = t + (k << 8);
            int wl = lin >> 6, c2 = lin & 63;
            int p = c2 ^ ((c2 >> 4) & 3);
            *(u64x2*)(mB + (wl << 10) + (c2 << 4)) = gm[k];
            *(u64x2*)(wB + (wl << 10) + (p << 4)) = gq[k];
        }
        __syncthreads();

        unsigned mo = (unsigned)(r0 << 3);
        unsigned qs = (unsigned)(cj << 6) + sx;
        #pragma unroll 2
        for (int w = 0; w < 16; ++w) {
            unsigned ml[16], ql[16];
            #pragma unroll
            for (int k = 0; k < 4; ++k) {
                uint4 a = *(const uint4*)(mB + mo + (k << 4));
                ml[4 * k + 0] = a.x; ml[4 * k + 1] = a.y;
                ml[4 * k + 2] = a.z; ml[4 * k + 3] = a.w;
                uint4 b = *(const uint4*)(wB + (qs ^ (unsigned)(k << 4)));
                ql[4 * k + 0] = b.x; ql[4 * k + 1] = b.y;
                ql[4 * k + 2] = b.z; ql[4 * k + 3] = b.w;
            }
            #pragma unroll
            for (int aa = 0; aa < 8; ++aa)
                #pragma unroll
                for (int bb = 0; bb < 8; ++bb) {
                    unsigned x0 = ml[2 * aa] & ql[2 * bb];
                    unsigned x1 = ml[2 * aa + 1] & ql[2 * bb + 1];
                    asm("v_bcnt_u32_b32 %0, %1, %0" : "+v"(cnt[aa][bb]) : "v"(x0));
                    asm("v_bcnt_u32_b32 %0, %1, %0" : "+v"(cnt[aa][bb]) : "v"(x1));
                }
            mo += 1024; qs += 1024;
        }
    }

    float part = 0.0f;
    const int c0 = cj << 3;
    #pragma unroll
    for (int aa = 0; aa < 8; ++aa) {
        size_t off = ((size_t)(b0 + r0 + aa) << 12) + (size_t)(j0 + c0);
        float ys[8], hs[8];
        *(float4*)&ys[0] = *(const float4*)(y + off);
        *(float4*)&ys[4] = *(const float4*)(y + off + 4);
        *(float4*)&hs[0] = *(const float4*)(yhat + off);
        *(float4*)&hs[4] = *(const float4*)(yhat + off + 4);
        #pragma unroll
        for (int bb = 0; bb < 8; ++bb) {
            float e = ys[bb] - hs[bb];
            float wgt = 0.1f * (float)cnt[aa][bb] + (ys[bb] != 0.0f ? 1.0f : 0.0f);
            part = fmaf(e * e, wgt, part);
        }
    }

    for (int off = 32; off; off >>= 1) part += __shfl_down(part, off, 64);
    float* red = (float*)mT;
    __syncthreads();
    if ((t & 63) == 0) red[t >> 6] = part;
    __syncthreads();
    if (t == 0)
        p3[(size_t)blockIdx.y * gridDim.x + blockIdx.x] =
            (double)red[0] + (double)red[1] + (double)red[2] + (double)red[3];
}

// ---------------- K4: final reduce + sqrt (np3 = valid p3 entries) ----------------
__global__ __launch_bounds__(256) void k4_final(
    const u64* __restrict__ pcnt, const double* __restrict__ p3, float* __restrict__ out,
    int np3)
{
    __shared__ double rs[4];
    __shared__ u64 rcc[4];
    double s3 = 0.0;
    u64 c = 0;
    for (int i = threadIdx.x; i < 2048; i += 256) c += pcnt[i];
    for (int i = threadIdx.x; i < np3; i += 256) s3 += p3[i];
    for (int off = 32; off; off >>= 1) {
        s3 += __shfl_down(s3, off, 64);
        c  += __shfl_down(c, off, 64);
    }
    int wv = threadIdx.x >> 6;
    if ((threadIdx.x & 63) == 0) { rs[wv] = s3; rcc[wv] = c; }
    __syncthreads();
    if (threadIdx.x == 0) {
        double S3 = rs[0] + rs[1] + rs[2] + rs[3];
        double C  = (double)(rcc[0] + rcc[1] + rcc[2] + rcc[3]);
        out[0] = (float)sqrt(S3 / C + 1e-6);
    }
}

extern "C" void kernel_launch(void* const* d_in, const int* in_sizes, int n_in,
                              void* d_out, int out_size, void* d_ws, size_t ws_size,
                              hipStream_t stream) {
    const float* yhat = (const float*)d_in[0];
    const float* y    = (const float*)d_in[1];
    const float* W    = (const float*)d_in[2];
    char* ws = (char*)d_ws;
    u64*    pcnt = (u64*)(ws + OFF_CNT);
    double* p3   = (double*)(ws + OFF_P3);

    if (ws_size >= WS_NEED) {
        u32* m8 = (u32*)(ws + OFF_M8);
        u32* bt = (u32*)(ws + OFF_BT);
        k12_prep<<<dim3(2048 + 4096), dim3(256), 0, stream>>>(y, W, m8, bt, pcnt);
        k3g_mfma<<<dim3(32, 16), dim3(512), 0, stream>>>(
            y, yhat, (const u8*)m8, (const u8*)bt, p3);
        k4_final<<<dim3(1), dim3(256), 0, stream>>>(pcnt, p3, (float*)d_out, 512);
    } else {
        u64* mbT = (u64*)(ws + OFF_MB);
        u64* wbT = (u64*)(ws + OFF_WB);
        k1_pack_mask<<<dim3(2048), dim3(256), 0, stream>>>(y, mbT, pcnt);
        k2_pack_w<<<dim3(64, 64), dim3(256), 0, stream>>>(W, wbT);
        k3_main<<<dim3(64, 32), dim3(256), 0, stream>>>(y, yhat, mbT, wbT, p3);
        k4_final<<<dim3(1), dim3(256), 0, stream>>>(pcnt, p3, (float*)d_out, 2048);
    }
}

// Round 24
// 186.454 us; speedup vs baseline: 1.2203x; 1.2203x over previous
//
#include <hip/hip_runtime.h>
#include <math.h>

typedef unsigned long long u64;
typedef unsigned int u32;
typedef unsigned char u8;
typedef __attribute__((ext_vector_type(2))) unsigned long long u64x2;
typedef __attribute__((ext_vector_type(4))) int i32x4;

#define NB 8192
#define NS 4096

// ---- ws layout ----
static const size_t OFF_CNT = 0;                            // pcnt[2048] u64
static const size_t OFF_P3  = 16384;                        // p3[<=2048] double
static const size_t OFF_M8  = 32768;                        // mask8 [8192][4096] i8
static const size_t OFF_BT  = OFF_M8 + (size_t)NB * NS;     // Bt [4096][4096] i8
static const size_t WS_NEED = OFF_BT + (size_t)NS * NS;     // ~48 MB (proven available)
static const size_t OFF_MB  = 32768;                        // popcount fallback layout
static const size_t OFF_WB  = OFF_MB + (size_t)64 * NB * 8;

__device__ __forceinline__ void gload_lds16(const void* g, void* l) {
    __builtin_amdgcn_global_load_lds(
        (const __attribute__((address_space(1))) unsigned int*)g,
        (__attribute__((address_space(3))) unsigned int*)l, 16, 0, 0);
}

// ================= i8-MFMA path =================

// K12: fused prep (R17-verified). g<2048: mask8+pcnt over y. g>=2048: Bt of W.
__global__ __launch_bounds__(256) void k12_prep(
    const float* __restrict__ y, const float* __restrict__ W,
    u32* __restrict__ m8, u32* __restrict__ bt, u64* __restrict__ pcnt)
{
    const int g = blockIdx.x;
    const int t = threadIdx.x;
    if (g < 2048) {
        __shared__ unsigned rc[4];
        const float4* y4 = (const float4*)y;
        size_t base = (size_t)g * 4096 + t;
        unsigned lcnt = 0;
        #pragma unroll 4
        for (int k = 0; k < 16; ++k) {
            float4 v = y4[base + (size_t)k * 256];
            unsigned b0 = v.x != 0.0f, b1 = v.y != 0.0f, b2 = v.z != 0.0f, b3 = v.w != 0.0f;
            lcnt += b0 + b1 + b2 + b3;
            m8[base + (size_t)k * 256] = b0 | (b1 << 8) | (b2 << 16) | (b3 << 24);
        }
        for (int off = 32; off; off >>= 1) lcnt += __shfl_down(lcnt, off, 64);
        if ((t & 63) == 0) rc[t >> 6] = lcnt;
        __syncthreads();
        if (t == 0) pcnt[g] = (u64)rc[0] + rc[1] + rc[2] + rc[3];
    } else {
        __shared__ float tile[64][65];
        const int gg = g - 2048;
        const int j0 = (gg & 63) * 64, i0 = (gg >> 6) * 64;
        #pragma unroll
        for (int k = 0; k < 16; ++k) {
            int lin = t + (k << 8);
            int r = lin >> 6, c = lin & 63;
            tile[r][c] = W[(size_t)(i0 + r) * NS + (j0 + c)];
        }
        __syncthreads();
        const int jj = t >> 2, ck = t & 3;
        u32 wd[4];
        #pragma unroll
        for (int gq = 0; gq < 4; ++gq) {
            u32 u = 0;
            #pragma unroll
            for (int bb = 0; bb < 4; ++bb)
                u |= (tile[ck * 16 + gq * 4 + bb][jj] != 0.0f ? 1u : 0u) << (8 * bb);
            wd[gq] = u;
        }
        uint4 out = make_uint4(wd[0], wd[1], wd[2], wd[3]);
        *(uint4*)&bt[(((size_t)(j0 + jj) << 12) + (size_t)(i0 + ck * 16)) >> 2] = out;
    }
}

// K3g v3 (R21, best verified: 148us, MfmaUtil 37%, 0 conflicts):
// 256x256 i8 GEMM, half-tile-granular staging interleave, counted vmcnt
// (2-deep, never 0 in-loop), XCD-chunked block swizzle, fused loss epilogue.
__global__ __launch_bounds__(512, 2) void k3g_mfma(
    const float* __restrict__ y, const float* __restrict__ yhat,
    const u8* __restrict__ m8, const u8* __restrict__ bt,
    double* __restrict__ p3)
{
    __shared__ alignas(16) u8 lds[131072];   // A: [d][h] 4x16KB @0; B: 4x16KB @65536
    const int lin = blockIdx.x + (blockIdx.y << 5);      // 0..511, x fastest
    const int swz = ((lin & 7) << 6) + (lin >> 3);       // chunked per-XCD (bijective)
    const int bx = swz & 31, by = swz >> 5;
    const int b0 = bx << 8;    // 32 row tiles (256 rows)
    const int j0 = by << 8;    // 16 col tiles (256 cols)
    const int t = threadIdx.x, l = t & 63, wv = t >> 6;   // 8 waves
    const int wr = wv >> 2, wc = wv & 3;                  // 2M x 4N

    const int srow = t >> 3;                    // 0..63
    const int schunk = (t & 7) ^ (srow & 7);    // pre-swizzled source chunk

    auto stageA = [&](int kt, int h) {
        const u8* src = m8 + ((size_t)(b0 + (h << 7) + srow) << 12)
                        + (size_t)((kt << 7) + (schunk << 4));
        u8* d = &lds[((((kt & 1) << 1) + h) << 14) + (wv << 10)];
        gload_lds16(src, d);
        gload_lds16(src + ((size_t)64 << 12), d + 8192);
    };
    auto stageB = [&](int kt, int h) {
        const u8* src = bt + ((size_t)(j0 + (h << 7) + srow) << 12)
                        + (size_t)((kt << 7) + (schunk << 4));
        u8* d = &lds[65536 + ((((kt & 1) << 1) + h) << 14) + (wv << 10)];
        gload_lds16(src, d);
        gload_lds16(src + ((size_t)64 << 12), d + 8192);
    };

    // frag read swizzle: slot = (ks*4 + qh) ^ (row&7), row&7 == l&7
    const int rl = l & 15, qh = l >> 4, rx = l & 7;
    const int sb0 = ((qh ^ rx) << 4);
    const int sb1 = (((4 + qh) ^ rx) << 4);
    const int bro = (wc & 1) << 6;   // B within-half base row

    i32x4 acc[8][4];
    #pragma unroll
    for (int i = 0; i < 8; ++i)
        #pragma unroll
        for (int j = 0; j < 4; ++j) acc[i][j] = (i32x4){0, 0, 0, 0};

    // prologue: tiles 0 and 1 (16 loads/thread)
    stageA(0, 0); stageA(0, 1); stageB(0, 0); stageB(0, 1);
    stageA(1, 0); stageA(1, 1); stageB(1, 0); stageB(1, 1);

    #pragma unroll 1
    for (int m = 0; m < 32; ++m) {
        const int d = m & 1;
        if (m == 0)       { asm volatile("s_waitcnt vmcnt(8)" ::: "memory"); }
        else if (m == 31) { asm volatile("s_waitcnt vmcnt(0)" ::: "memory"); }
        else              { asm volatile("s_waitcnt vmcnt(4)" ::: "memory"); }
        __builtin_amdgcn_s_barrier();          // A(m), B(m) published
        asm volatile("" ::: "memory");

        const u8* LA = &lds[(((d << 1) + wr) << 14)];
        const u8* LB = &lds[65536 + (((d << 1) + (wc >> 1)) << 14)];

        i32x4 b[4][2];
        #pragma unroll
        for (int q = 0; q < 4; ++q) {
            if (q == 0) { if (m >= 1 && m <= 30) stageA(m + 1, 0); }
            else if (q == 1) { if (m >= 1 && m <= 30) stageA(m + 1, 1); }
            else if (q == 2) { if (m <= 29) stageB(m + 2, 0); }
            else             { if (m <= 29) stageB(m + 2, 1); }

            if (q == 0) {   // B for the whole tile, kept in regs
                #pragma unroll
                for (int fc = 0; fc < 4; ++fc) {
                    const int lr = bro + (fc << 4) + rl;
                    b[fc][0] = *(const i32x4*)&LB[(lr << 7) + sb0];
                    b[fc][1] = *(const i32x4*)&LB[(lr << 7) + sb1];
                }
            }
            i32x4 a[2][2];
            #pragma unroll
            for (int i = 0; i < 2; ++i) {
                const int lr = (((q << 1) + i) << 4) + rl;
                a[i][0] = *(const i32x4*)&LA[(lr << 7) + sb0];
                a[i][1] = *(const i32x4*)&LA[(lr << 7) + sb1];
            }
            __builtin_amdgcn_s_setprio(1);
            #pragma unroll
            for (int i = 0; i < 2; ++i)
                #pragma unroll
                for (int fc = 0; fc < 4; ++fc) {
                    acc[2 * q + i][fc] = __builtin_amdgcn_mfma_i32_16x16x64_i8(
                        a[i][0], b[fc][0], acc[2 * q + i][fc], 0, 0, 0);
                    acc[2 * q + i][fc] = __builtin_amdgcn_mfma_i32_16x16x64_i8(
                        a[i][1], b[fc][1], acc[2 * q + i][fc], 0, 0, 0);
                }
            __builtin_amdgcn_s_setprio(0);

            if (q == 0) {   // release B[d]
                asm volatile("" ::: "memory");
                __builtin_amdgcn_s_barrier();
                asm volatile("" ::: "memory");
            }
        }
    }

    // epilogue: C/D map col=l&15, row=(l>>4)*4+q (R10-verified), fused loss
    float part = 0.0f;
    const int col = j0 + (wc << 6) + rl;
    #pragma unroll
    for (int fr = 0; fr < 8; ++fr)
        #pragma unroll
        for (int q = 0; q < 4; ++q) {
            size_t rbase = ((size_t)(b0 + (wr << 7) + (fr << 4) + (qh << 2) + q) << 12) + col;
            #pragma unroll
            for (int fc = 0; fc < 4; ++fc) {
                float yv = y[rbase + (fc << 4)];
                float hv = yhat[rbase + (fc << 4)];
                float e = yv - hv;
                float wgt = 0.1f * (float)acc[fr][fc][q] + (yv != 0.0f ? 1.0f : 0.0f);
                part = fmaf(e * e, wgt, part);
            }
        }

    for (int off = 32; off; off >>= 1) part += __shfl_down(part, off, 64);
    float* red = (float*)lds;
    __syncthreads();   // drains all counters; safe to alias LDS
    if ((t & 63) == 0) red[t >> 6] = part;
    __syncthreads();
    if (t == 0) {
        float s = 0.0f;
        #pragma unroll
        for (int i = 0; i < 8; ++i) s += red[i];
        p3[swz] = (double)s;
    }
}

// ================= popcount fallback path (R8, passing) =================

__global__ __launch_bounds__(256) void k1_pack_mask(
    const float* __restrict__ y, u64* __restrict__ mbT, u64* __restrict__ pcnt)
{
    __shared__ unsigned rc[4];
    const unsigned t = threadIdx.x;
    const unsigned lane = t & 63;
    const float4* y4 = (const float4*)y;
    u64 qi = (u64)blockIdx.x * 256 + t;
    const u64 stride = (u64)2048 * 256;
    unsigned lcnt = 0;
    #pragma unroll 4
    for (int it = 0; it < 16; ++it, qi += stride) {
        float4 v = y4[qi];
        u64 b0 = __ballot(v.x != 0.0f);
        u64 b1 = __ballot(v.y != 0.0f);
        u64 b2 = __ballot(v.z != 0.0f);
        u64 b3 = __ballot(v.w != 0.0f);
        lcnt += (v.x != 0.0f) + (v.y != 0.0f) + (v.z != 0.0f) + (v.w != 0.0f);
        if (lane < 4) {
            unsigned sh = lane << 4;
            u64 word = ((b0 >> sh) & 0xFFFFull)
                     | (((b1 >> sh) & 0xFFFFull) << 16)
                     | (((b2 >> sh) & 0xFFFFull) << 32)
                     | (((b3 >> sh) & 0xFFFFull) << 48);
            u64 gw = ((qi - lane) >> 4) + lane;
            mbT[((gw & 63) << 13) + (gw >> 6)] = word;
        }
    }
    for (int off = 32; off; off >>= 1) lcnt += __shfl_down(lcnt, off, 64);
    if ((t & 63) == 0) rc[t >> 6] = lcnt;
    __syncthreads();
    if (t == 0) pcnt[blockIdx.x] = (u64)rc[0] + rc[1] + rc[2] + rc[3];
}

__global__ __launch_bounds__(256) void k2_pack_w(
    const float* __restrict__ W, u64* __restrict__ wbT)
{
    __shared__ float tile[64][65];
    const int j0 = blockIdx.x * 64;
    const int w  = blockIdx.y;
    const int i0 = w * 64;
    const int t = threadIdx.x;
    #pragma unroll
    for (int k = 0; k < 16; ++k) {
        int lin = t + (k << 8);
        int r = lin >> 6, c = lin & 63;
        tile[r][c] = W[(size_t)(i0 + r) * NS + (j0 + c)];
    }
    __syncthreads();
    const int lane = t & 63;
    const int wvv = t >> 6;
    const int pr = ((lane & 15) << 2) + (lane >> 4);
    for (int jj = wvv; jj < 64; jj += 4) {
        u64 bal = __ballot(tile[pr][jj] != 0.0f);
        if (lane == 0) wbT[((size_t)w << 12) + (j0 + jj)] = bal;
    }
}

__global__ __launch_bounds__(256) void k3_main(
    const float* __restrict__ y, const float* __restrict__ yhat,
    const u64* __restrict__ mbT, const u64* __restrict__ wbT,
    double* __restrict__ p3)
{
    __shared__ alignas(16) u64 mT[16 * 128];
    __shared__ alignas(16) u64 wT[16 * 128];
    const int b0 = blockIdx.x << 7;
    const int j0 = blockIdx.y << 7;
    const int t  = threadIdx.x;
    const int r0 = (t >> 4) << 3;
    const int cj = t & 15;
    const unsigned sx = ((unsigned)cj >> 2) << 4;

    unsigned cnt[8][8];
    #pragma unroll
    for (int a = 0; a < 8; ++a)
        #pragma unroll
        for (int b = 0; b < 8; ++b) cnt[a][b] = 0;

    char* mB = (char*)mT;
    char* wB = (char*)wT;

    #pragma unroll 1
    for (int s = 0; s < 4; ++s) {
        u64x2 gm[4], gq[4];
        #pragma unroll
        for (int k = 0; k < 4; ++k) {
            int lin = t + (k << 8);
            int wl = (s << 4) + (lin >> 6), c2 = lin & 63;
            gm[k] = *(const u64x2*)&mbT[((size_t)wl << 13) + b0 + 2 * c2];
            gq[k] = *(const u64x2*)&wbT[((size_t)wl << 12) + j0 + 2 * c2];
        }
        __syncthreads();
        #pragma unroll
        for (int k = 0; k < 4; ++k) {
            int lin = t + (k << 8);
            int wl = lin >> 6, c2 = lin & 63;
            int p = c2 ^ ((c2 >> 4) & 3);
            *(u64x2*)(mB + (wl << 10) + (c2 << 4)) = gm[k];
            *(u64x2*)(wB + (wl << 10) + (p << 4)) = gq[k];
        }
        __syncthreads();

        unsigned mo = (unsigned)(r0 << 3);
        unsigned qs = (unsigned)(cj << 6) + sx;
        #pragma unroll 2
        for (int w = 0; w < 16; ++w) {
            unsigned ml[16], ql[16];
            #pragma unroll
            for (int k = 0; k < 4; ++k) {
                uint4 a = *(const uint4*)(mB + mo + (k << 4));
                ml[4 * k + 0] = a.x; ml[4 * k + 1] = a.y;
                ml[4 * k + 2] = a.z; ml[4 * k + 3] = a.w;
                uint4 b = *(const uint4*)(wB + (qs ^ (unsigned)(k << 4)));
                ql[4 * k + 0] = b.x; ql[4 * k + 1] = b.y;
                ql[4 * k + 2] = b.z; ql[4 * k + 3] = b.w;
            }
            #pragma unroll
            for (int aa = 0; aa < 8; ++aa)
                #pragma unroll
                for (int bb = 0; bb < 8; ++bb) {
                    unsigned x0 = ml[2 * aa] & ql[2 * bb];
                    unsigned x1 = ml[2 * aa + 1] & ql[2 * bb + 1];
                    asm("v_bcnt_u32_b32 %0, %1, %0" : "+v"(cnt[aa][bb]) : "v"(x0));
                    asm("v_bcnt_u32_b32 %0, %1, %0" : "+v"(cnt[aa][bb]) : "v"(x1));
                }
            mo += 1024; qs += 1024;
        }
    }

    float part = 0.0f;
    const int c0 = cj << 3;
    #pragma unroll
    for (int aa = 0; aa < 8; ++aa) {
        size_t off = ((size_t)(b0 + r0 + aa) << 12) + (size_t)(j0 + c0);
        float ys[8], hs[8];
        *(float4*)&ys[0] = *(const float4*)(y + off);
        *(float4*)&ys[4] = *(const float4*)(y + off + 4);
        *(float4*)&hs[0] = *(const float4*)(yhat + off);
        *(float4*)&hs[4] = *(const float4*)(yhat + off + 4);
        #pragma unroll
        for (int bb = 0; bb < 8; ++bb) {
            float e = ys[bb] - hs[bb];
            float wgt = 0.1f * (float)cnt[aa][bb] + (ys[bb] != 0.0f ? 1.0f : 0.0f);
            part = fmaf(e * e, wgt, part);
        }
    }

    for (int off = 32; off; off >>= 1) part += __shfl_down(part, off, 64);
    float* red = (float*)mT;
    __syncthreads();
    if ((t & 63) == 0) red[t >> 6] = part;
    __syncthreads();
    if (t == 0)
        p3[(size_t)blockIdx.y * gridDim.x + blockIdx.x] =
            (double)red[0] + (double)red[1] + (double)red[2] + (double)red[3];
}

// ---------------- K4: final reduce + sqrt (np3 = valid p3 entries) ----------------
__global__ __launch_bounds__(256) void k4_final(
    const u64* __restrict__ pcnt, const double* __restrict__ p3, float* __restrict__ out,
    int np3)
{
    __shared__ double rs[4];
    __shared__ u64 rcc[4];
    double s3 = 0.0;
    u64 c = 0;
    for (int i = threadIdx.x; i < 2048; i += 256) c += pcnt[i];
    for (int i = threadIdx.x; i < np3; i += 256) s3 += p3[i];
    for (int off = 32; off; off >>= 1) {
        s3 += __shfl_down(s3, off, 64);
        c  += __shfl_down(c, off, 64);
    }
    int wv = threadIdx.x >> 6;
    if ((threadIdx.x & 63) == 0) { rs[wv] = s3; rcc[wv] = c; }
    __syncthreads();
    if (threadIdx.x == 0) {
        double S3 = rs[0] + rs[1] + rs[2] + rs[3];
        double C  = (double)(rcc[0] + rcc[1] + rcc[2] + rcc[3]);
        out[0] = (float)sqrt(S3 / C + 1e-6);
    }
}

extern "C" void kernel_launch(void* const* d_in, const int* in_sizes, int n_in,
                              void* d_out, int out_size, void* d_ws, size_t ws_size,
                              hipStream_t stream) {
    const float* yhat = (const float*)d_in[0];
    const float* y    = (const float*)d_in[1];
    const float* W    = (const float*)d_in[2];
    char* ws = (char*)d_ws;
    u64*    pcnt = (u64*)(ws + OFF_CNT);
    double* p3   = (double*)(ws + OFF_P3);

    if (ws_size >= WS_NEED) {
        u32* m8 = (u32*)(ws + OFF_M8);
        u32* bt = (u32*)(ws + OFF_BT);
        k12_prep<<<dim3(2048 + 4096), dim3(256), 0, stream>>>(y, W, m8, bt, pcnt);
        k3g_mfma<<<dim3(32, 16), dim3(512), 0, stream>>>(
            y, yhat, (const u8*)m8, (const u8*)bt, p3);
        k4_final<<<dim3(1), dim3(256), 0, stream>>>(pcnt, p3, (float*)d_out, 512);
    } else {
        u64* mbT = (u64*)(ws + OFF_MB);
        u64* wbT = (u64*)(ws + OFF_WB);
        k1_pack_mask<<<dim3(2048), dim3(256), 0, stream>>>(y, mbT, pcnt);
        k2_pack_w<<<dim3(64, 64), dim3(256), 0, stream>>>(W, wbT);
        k3_main<<<dim3(64, 32), dim3(256), 0, stream>>>(y, yhat, mbT, wbT, p3);
        k4_final<<<dim3(1), dim3(256), 0, stream>>>(pcnt, p3, (float*)d_out, 2048);
    }
}